// Round 2
// baseline (2110.743 us; speedup 1.0000x reference)
//
#include <hip/hip_runtime.h>

// 1-NN: for each query x_i (8192 x 128 f32), argmin_j over train_pts (32768 x 128 f32)
// of squared distance; output train_label[argmin]. argmin(x2+y2-2xy) == argmin(0.5*y2 - xy).
//
// Round 2: x is block-uniform -> read it straight from global with uniform
// addresses so hipcc emits s_load (scalar cache, SGPRs). v_fma_f32 takes the
// x value as its one allowed SGPR operand. This removes all LDS traffic from
// the inner loop (round 1 was LDS-issue-bound: 8 ds_read_b128 per 128 VALU
// cycles x 8 waves/CU ~ 3x oversubscribed -> VALUBusy 44%).

#define NQ 8192
#define NM 32768
#define ND 128
#define QT 16    // queries per block
#define BT 256   // threads per block

// Precompute h[j] = 0.5 * ||y_j||^2 into workspace.
__global__ void h_kernel(const float* __restrict__ y, float* __restrict__ h) {
  int j = blockIdx.x * blockDim.x + threadIdx.x;
  if (j >= NM) return;
  const float4* __restrict__ yp = (const float4*)(y + (size_t)j * ND);
  float s = 0.f;
#pragma unroll
  for (int u = 0; u < ND / 4; ++u) {
    float4 v = yp[u];
    s = fmaf(v.x, v.x, s);
    s = fmaf(v.y, v.y, s);
    s = fmaf(v.z, v.z, s);
    s = fmaf(v.w, v.w, s);
  }
  h[j] = 0.5f * s;
}

template <int USE_H>
__global__ __launch_bounds__(BT, 2) void nn_kernel(
    const float* __restrict__ x, const float* __restrict__ y,
    const float* __restrict__ lab, const float* __restrict__ h,
    float* __restrict__ out) {
  const int t = threadIdx.x;
  const int q0 = blockIdx.x * QT;

  float bv[QT];
  int bi[QT];
#pragma unroll
  for (int q = 0; q < QT; ++q) { bv[q] = 3.4e38f; bi[q] = 0; }

  // Each iteration: this thread handles train rows j0 = it*512 + t and j1 = j0 + 256.
  for (int it = 0; it < NM / (2 * BT); ++it) {
    const int j0 = it * (2 * BT) + t;
    const int j1 = j0 + BT;
    const float4* __restrict__ yp0 = (const float4*)(y + (size_t)j0 * ND);
    const float4* __restrict__ yp1 = (const float4*)(y + (size_t)j1 * ND);
    float acc0[QT], acc1[QT];
#pragma unroll
    for (int q = 0; q < QT; ++q) { acc0[q] = 0.f; acc1[q] = 0.f; }
    float y20 = 0.f, y21 = 0.f;
#pragma unroll 1   // keep k-chunk loop rolled: bounds live y-registers to 2x32 floats
    for (int kc = 0; kc < ND / 32; ++kc) {
      float4 a0[8], a1[8];
#pragma unroll
      for (int u = 0; u < 8; ++u) {
        a0[u] = yp0[kc * 8 + u];
        a1[u] = yp1[kc * 8 + u];
      }
      if (USE_H == 0) {
#pragma unroll
        for (int u = 0; u < 8; ++u) {
          y20 = fmaf(a0[u].x, a0[u].x, y20);
          y20 = fmaf(a0[u].y, a0[u].y, y20);
          y20 = fmaf(a0[u].z, a0[u].z, y20);
          y20 = fmaf(a0[u].w, a0[u].w, y20);
          y21 = fmaf(a1[u].x, a1[u].x, y21);
          y21 = fmaf(a1[u].y, a1[u].y, y21);
          y21 = fmaf(a1[u].z, a1[u].z, y21);
          y21 = fmaf(a1[u].w, a1[u].w, y21);
        }
      }
#pragma unroll
      for (int q = 0; q < QT; ++q) {
        // Block-uniform address (blockIdx + constants only) -> scalar loads
        // through the scalar cache; x values land in SGPRs.
        const float* __restrict__ xq = x + (size_t)(q0 + q) * ND + kc * 32;
        float s0 = acc0[q], s1 = acc1[q];
#pragma unroll
        for (int u = 0; u < 8; ++u) {
          const float4 xv = *(const float4*)(xq + u * 4);
          s0 = fmaf(a0[u].x, xv.x, s0);
          s0 = fmaf(a0[u].y, xv.y, s0);
          s0 = fmaf(a0[u].z, xv.z, s0);
          s0 = fmaf(a0[u].w, xv.w, s0);
          s1 = fmaf(a1[u].x, xv.x, s1);
          s1 = fmaf(a1[u].y, xv.y, s1);
          s1 = fmaf(a1[u].z, xv.z, s1);
          s1 = fmaf(a1[u].w, xv.w, s1);
        }
        acc0[q] = s0;
        acc1[q] = s1;
      }
    }
    float h0, h1;
    if (USE_H) {
      h0 = h[j0];
      h1 = h[j1];
    } else {
      h0 = 0.5f * y20;
      h1 = 0.5f * y21;
    }
#pragma unroll
    for (int q = 0; q < QT; ++q) {
      const float s0 = h0 - acc0[q];
      const float s1 = h1 - acc1[q];
      // strict < keeps earliest index (j0 < j1, and j grows with it): matches jnp.argmin ties
      if (s0 < bv[q]) { bv[q] = s0; bi[q] = j0; }
      if (s1 < bv[q]) { bv[q] = s1; bi[q] = j1; }
    }
  }

  // Cross-thread reduction: wave shuffle then tiny LDS combine.
  __shared__ float rv[4][QT];
  __shared__ int ri[4][QT];
  const int lane = t & 63, w = t >> 6;
#pragma unroll
  for (int q = 0; q < QT; ++q) {
    float v = bv[q];
    int ix = bi[q];
    for (int off = 32; off; off >>= 1) {
      const float ov = __shfl_down(v, off);
      const int oi = __shfl_down(ix, off);
      if (ov < v || (ov == v && oi < ix)) { v = ov; ix = oi; }
    }
    if (lane == 0) { rv[w][q] = v; ri[w][q] = ix; }
  }
  __syncthreads();
  if (t < QT) {
    float v = rv[0][t];
    int ix = ri[0][t];
#pragma unroll
    for (int w2 = 1; w2 < 4; ++w2) {
      const float ov = rv[w2][t];
      const int oi = ri[w2][t];
      if (ov < v || (ov == v && oi < ix)) { v = ov; ix = oi; }
    }
    out[q0 + t] = lab[ix];
  }
}

extern "C" void kernel_launch(void* const* d_in, const int* in_sizes, int n_in,
                              void* d_out, int out_size, void* d_ws, size_t ws_size,
                              hipStream_t stream) {
  const float* x = (const float*)d_in[0];
  const float* y = (const float*)d_in[1];
  const float* lab = (const float*)d_in[2];
  float* out = (float*)d_out;

  if (ws_size >= (size_t)NM * sizeof(float)) {
    float* h = (float*)d_ws;
    h_kernel<<<NM / BT, BT, 0, stream>>>(y, h);
    nn_kernel<1><<<NQ / QT, BT, 0, stream>>>(x, y, lab, h, out);
  } else {
    nn_kernel<0><<<NQ / QT, BT, 0, stream>>>(x, y, lab, nullptr, out);
  }
}

// Round 3
// 1224.754 us; speedup vs baseline: 1.7234x; 1.7234x over previous
//
#include <hip/hip_runtime.h>

// 1-NN: for each query x_i (8192x128 f32), argmin_j over train_pts (32768x128 f32)
// of squared distance; output train_label[argmin]. argmin(x2+y2-2xy) == argmin(0.5*y2 - xy).
//
// Round 3: rounds 1+2 were bound by the y access pattern (row-per-thread ->
// 64 distinct cachelines per load instr -> L2 transaction-rate wall + L3 latency).
// Fix: pre-transpose y to yT[128][32768]; thread owns 8 ADJACENT rows -> fully
// coalesced dwordx4 loads. Grid = q-tiles x 8 j-slices with slice = bid&7 so each
// XCD keeps its 2MB slice L2-resident. Partial (min,idx) per (query,slice) in ws,
// reduced by a tiny second kernel. Dot-product fmaf chains are k-ascending ->
// bit-identical to the round-2 kernel that scored absmax 0.0.

#define NQ 8192
#define NM 32768
#define ND 128
#define QT 8      // queries per block (phase A)
#define BT 256    // threads per block
#define NSLICE 8
#define SLICE (NM / NSLICE)       // 4096 rows
#define RPT 8                     // adjacent rows per thread
#define ITS (SLICE / (BT * RPT))  // 2

// ---------- transpose y[32768][128] -> yT[128][32768] ----------
#define TJ 64
#define TC 32
__global__ void t_kernel(const float* __restrict__ y, float* __restrict__ yT) {
  __shared__ float tile[TC][TJ + 1];
  const int bx = blockIdx.x;
  const int c0 = (bx % (ND / TC)) * TC;
  const int j0 = (bx / (ND / TC)) * TJ;
  const int tc = threadIdx.x % TC, tj = threadIdx.x / TC;  // 32 x 8
#pragma unroll
  for (int p = 0; p < TJ / 8; ++p) {
    const int j = tj + p * 8;
    tile[tc][j] = y[(size_t)(j0 + j) * ND + c0 + tc];
  }
  __syncthreads();
  const int wj = threadIdx.x % TJ, wc0 = threadIdx.x / TJ;  // 64 x 4
#pragma unroll
  for (int p = 0; p < TC / 4; ++p) {
    const int c = wc0 + p * 4;
    yT[(size_t)(c0 + c) * NM + j0 + wj] = tile[c][wj];
  }
}

// ---------- h[j] = 0.5*||y_j||^2 from yT (coalesced across j) ----------
__global__ void h2_kernel(const float* __restrict__ yT, float* __restrict__ h) {
  const int j = blockIdx.x * blockDim.x + threadIdx.x;
  if (j >= NM) return;
  float s = 0.f;
#pragma unroll
  for (int c = 0; c < ND; ++c) {
    const float v = yT[(size_t)c * NM + j];
    s = fmaf(v, v, s);
  }
  h[j] = 0.5f * s;
}

// ---------- phase A helpers ----------
__device__ __forceinline__ void loadw(float4 yv[4][2], const float* __restrict__ yb, int w) {
#pragma unroll
  for (int c = 0; c < 4; ++c) {
    const float4* __restrict__ p = (const float4*)(yb + (size_t)(4 * w + c) * NM);
    yv[c][0] = p[0];
    yv[c][1] = p[1];
  }
}

__device__ __forceinline__ void fmaw(float (&acc)[QT][RPT], const float4 (&yv)[4][2],
                                     const float (*__restrict__ xs)[ND], int w) {
#pragma unroll
  for (int q = 0; q < QT; ++q) {
    const float4 xv = *(const float4*)&xs[q][4 * w];  // uniform addr -> LDS broadcast
    const float xc[4] = {xv.x, xv.y, xv.z, xv.w};
#pragma unroll
    for (int c = 0; c < 4; ++c) {
#pragma unroll
      for (int g = 0; g < 2; ++g) {
        const float4 yv4 = yv[c][g];
        acc[q][g * 4 + 0] = fmaf(yv4.x, xc[c], acc[q][g * 4 + 0]);
        acc[q][g * 4 + 1] = fmaf(yv4.y, xc[c], acc[q][g * 4 + 1]);
        acc[q][g * 4 + 2] = fmaf(yv4.z, xc[c], acc[q][g * 4 + 2]);
        acc[q][g * 4 + 3] = fmaf(yv4.w, xc[c], acc[q][g * 4 + 3]);
      }
    }
  }
}

// ---------- phase A: per (q-tile, slice) partial argmin ----------
__global__ __launch_bounds__(BT, 2) void nnA_kernel(
    const float* __restrict__ x, const float* __restrict__ yT,
    const float* __restrict__ h, float* __restrict__ pval, int* __restrict__ pidx) {
  __shared__ float xs[QT][ND];
  const int t = threadIdx.x;
  const int slice = blockIdx.x & (NSLICE - 1);
  const int qt = blockIdx.x >> 3;
  const int q0 = qt * QT;

  for (int i = t; i < QT * ND; i += BT) xs[i >> 7][i & 127] = x[(size_t)q0 * ND + i];
  __syncthreads();

  float bv[QT];
  int bi[QT];
#pragma unroll
  for (int q = 0; q < QT; ++q) { bv[q] = 3.4e38f; bi[q] = 0; }

#pragma unroll 1
  for (int it = 0; it < ITS; ++it) {
    const int jb = slice * SLICE + it * (BT * RPT) + t * RPT;  // 8 adjacent rows
    const float* __restrict__ yb = yT + jb;
    float acc[QT][RPT];
#pragma unroll
    for (int q = 0; q < QT; ++q)
#pragma unroll
      for (int r = 0; r < RPT; ++r) acc[q][r] = 0.f;

    // 32 windows of 4 columns, double-buffered y regs
    float4 yA[4][2], yB[4][2];
    loadw(yA, yb, 0);
#pragma unroll 1
    for (int w2 = 0; w2 < 15; ++w2) {
      loadw(yB, yb, 2 * w2 + 1);
      fmaw(acc, yA, xs, 2 * w2);
      loadw(yA, yb, 2 * w2 + 2);
      fmaw(acc, yB, xs, 2 * w2 + 1);
    }
    loadw(yB, yb, 31);
    fmaw(acc, yA, xs, 30);
    fmaw(acc, yB, xs, 31);

    const float4* __restrict__ hp = (const float4*)(h + jb);
    const float4 h0 = hp[0], h1 = hp[1];
    const float hr[8] = {h0.x, h0.y, h0.z, h0.w, h1.x, h1.y, h1.z, h1.w};
#pragma unroll
    for (int q = 0; q < QT; ++q)
#pragma unroll
      for (int r = 0; r < RPT; ++r) {
        const float s = hr[r] - acc[q][r];
        if (s < bv[q]) { bv[q] = s; bi[q] = jb + r; }  // strict <, r ascending: earliest j
      }
  }

  // cross-thread reduce: lanes/threads are ordered by j, lexicographic (val, idx) min
  __shared__ float rv[4][QT];
  __shared__ int ri[4][QT];
  const int lane = t & 63, w = t >> 6;
#pragma unroll
  for (int q = 0; q < QT; ++q) {
    float v = bv[q];
    int ix = bi[q];
    for (int off = 32; off; off >>= 1) {
      const float ov = __shfl_down(v, off);
      const int oi = __shfl_down(ix, off);
      if (ov < v || (ov == v && oi < ix)) { v = ov; ix = oi; }
    }
    if (lane == 0) { rv[w][q] = v; ri[w][q] = ix; }
  }
  __syncthreads();
  if (t < QT) {
    float v = rv[0][t];
    int ix = ri[0][t];
#pragma unroll
    for (int w2 = 1; w2 < 4; ++w2) {
      const float ov = rv[w2][t];
      const int oi = ri[w2][t];
      if (ov < v || (ov == v && oi < ix)) { v = ov; ix = oi; }
    }
    pval[(size_t)(q0 + t) * NSLICE + slice] = v;
    pidx[(size_t)(q0 + t) * NSLICE + slice] = ix;
  }
}

// ---------- phase B: reduce slices, gather label ----------
__global__ void nnB_kernel(const float* __restrict__ pval, const int* __restrict__ pidx,
                           const float* __restrict__ lab, float* __restrict__ out) {
  const int q = blockIdx.x * blockDim.x + threadIdx.x;
  if (q >= NQ) return;
  const float* __restrict__ pv = pval + (size_t)q * NSLICE;
  const int* __restrict__ pi = pidx + (size_t)q * NSLICE;
  float v = pv[0];
  int ix = pi[0];
#pragma unroll
  for (int s = 1; s < NSLICE; ++s) {
    const float ov = pv[s];
    const int oi = pi[s];
    if (ov < v || (ov == v && oi < ix)) { v = ov; ix = oi; }
  }
  out[q] = lab[ix];
}

// ---------- fallback (round-2 kernel, known-passing) ----------
template <int USE_H>
__global__ __launch_bounds__(BT, 2) void nn_fallback(
    const float* __restrict__ x, const float* __restrict__ y,
    const float* __restrict__ lab, const float* __restrict__ h,
    float* __restrict__ out) {
  const int t = threadIdx.x;
  const int q0 = blockIdx.x * 16;
  float bv[16];
  int bi[16];
#pragma unroll
  for (int q = 0; q < 16; ++q) { bv[q] = 3.4e38f; bi[q] = 0; }
  for (int it = 0; it < NM / 512; ++it) {
    const int j0 = it * 512 + t;
    const int j1 = j0 + 256;
    const float4* __restrict__ yp0 = (const float4*)(y + (size_t)j0 * ND);
    const float4* __restrict__ yp1 = (const float4*)(y + (size_t)j1 * ND);
    float acc0[16], acc1[16];
#pragma unroll
    for (int q = 0; q < 16; ++q) { acc0[q] = 0.f; acc1[q] = 0.f; }
    float y20 = 0.f, y21 = 0.f;
#pragma unroll 1
    for (int kc = 0; kc < 4; ++kc) {
      float4 a0[8], a1[8];
#pragma unroll
      for (int u = 0; u < 8; ++u) { a0[u] = yp0[kc * 8 + u]; a1[u] = yp1[kc * 8 + u]; }
      if (USE_H == 0) {
#pragma unroll
        for (int u = 0; u < 8; ++u) {
          y20 = fmaf(a0[u].x, a0[u].x, y20); y20 = fmaf(a0[u].y, a0[u].y, y20);
          y20 = fmaf(a0[u].z, a0[u].z, y20); y20 = fmaf(a0[u].w, a0[u].w, y20);
          y21 = fmaf(a1[u].x, a1[u].x, y21); y21 = fmaf(a1[u].y, a1[u].y, y21);
          y21 = fmaf(a1[u].z, a1[u].z, y21); y21 = fmaf(a1[u].w, a1[u].w, y21);
        }
      }
#pragma unroll
      for (int q = 0; q < 16; ++q) {
        const float* __restrict__ xq = x + (size_t)(q0 + q) * ND + kc * 32;
        float s0 = acc0[q], s1 = acc1[q];
#pragma unroll
        for (int u = 0; u < 8; ++u) {
          const float4 xv = *(const float4*)(xq + u * 4);
          s0 = fmaf(a0[u].x, xv.x, s0); s0 = fmaf(a0[u].y, xv.y, s0);
          s0 = fmaf(a0[u].z, xv.z, s0); s0 = fmaf(a0[u].w, xv.w, s0);
          s1 = fmaf(a1[u].x, xv.x, s1); s1 = fmaf(a1[u].y, xv.y, s1);
          s1 = fmaf(a1[u].z, xv.z, s1); s1 = fmaf(a1[u].w, xv.w, s1);
        }
        acc0[q] = s0; acc1[q] = s1;
      }
    }
    float h0, h1;
    if (USE_H) { h0 = h[j0]; h1 = h[j1]; }
    else { h0 = 0.5f * y20; h1 = 0.5f * y21; }
#pragma unroll
    for (int q = 0; q < 16; ++q) {
      const float s0 = h0 - acc0[q];
      const float s1 = h1 - acc1[q];
      if (s0 < bv[q]) { bv[q] = s0; bi[q] = j0; }
      if (s1 < bv[q]) { bv[q] = s1; bi[q] = j1; }
    }
  }
  __shared__ float rv[4][16];
  __shared__ int ri[4][16];
  const int lane = t & 63, w = t >> 6;
#pragma unroll
  for (int q = 0; q < 16; ++q) {
    float v = bv[q];
    int ix = bi[q];
    for (int off = 32; off; off >>= 1) {
      const float ov = __shfl_down(v, off);
      const int oi = __shfl_down(ix, off);
      if (ov < v || (ov == v && oi < ix)) { v = ov; ix = oi; }
    }
    if (lane == 0) { rv[w][q] = v; ri[w][q] = ix; }
  }
  __syncthreads();
  if (t < 16) {
    float v = rv[0][t];
    int ix = ri[0][t];
#pragma unroll
    for (int w2 = 1; w2 < 4; ++w2) {
      const float ov = rv[w2][t];
      const int oi = ri[w2][t];
      if (ov < v || (ov == v && oi < ix)) { v = ov; ix = oi; }
    }
    out[q0 + t] = lab[ix];
  }
}

__global__ void hrow_kernel(const float* __restrict__ y, float* __restrict__ h) {
  const int j = blockIdx.x * blockDim.x + threadIdx.x;
  if (j >= NM) return;
  const float4* __restrict__ yp = (const float4*)(y + (size_t)j * ND);
  float s = 0.f;
#pragma unroll
  for (int u = 0; u < ND / 4; ++u) {
    const float4 v = yp[u];
    s = fmaf(v.x, v.x, s); s = fmaf(v.y, v.y, s);
    s = fmaf(v.z, v.z, s); s = fmaf(v.w, v.w, s);
  }
  h[j] = 0.5f * s;
}

extern "C" void kernel_launch(void* const* d_in, const int* in_sizes, int n_in,
                              void* d_out, int out_size, void* d_ws, size_t ws_size,
                              hipStream_t stream) {
  const float* x = (const float*)d_in[0];
  const float* y = (const float*)d_in[1];
  const float* lab = (const float*)d_in[2];
  float* out = (float*)d_out;

  const size_t yt_b = (size_t)NM * ND * 4;        // 16 MB
  const size_t h_b = (size_t)NM * 4;              // 128 KB
  const size_t pv_b = (size_t)NQ * NSLICE * 4;    // 256 KB
  const size_t need = yt_b + h_b + 2 * pv_b;

  if (ws_size >= need) {
    float* yT = (float*)d_ws;
    float* h = (float*)((char*)d_ws + yt_b);
    float* pval = (float*)((char*)d_ws + yt_b + h_b);
    int* pidx = (int*)((char*)d_ws + yt_b + h_b + pv_b);
    t_kernel<<<(ND / TC) * (NM / TJ), BT, 0, stream>>>(y, yT);
    h2_kernel<<<NM / BT, BT, 0, stream>>>(yT, h);
    nnA_kernel<<<(NQ / QT) * NSLICE, BT, 0, stream>>>(x, yT, h, pval, pidx);
    nnB_kernel<<<(NQ + BT - 1) / BT, BT, 0, stream>>>(pval, pidx, lab, out);
  } else if (ws_size >= h_b) {
    float* h = (float*)d_ws;
    hrow_kernel<<<NM / BT, BT, 0, stream>>>(y, h);
    nn_fallback<1><<<NQ / 16, BT, 0, stream>>>(x, y, lab, h, out);
  } else {
    nn_fallback<0><<<NQ / 16, BT, 0, stream>>>(x, y, lab, nullptr, out);
  }
}

// Round 4
// 531.632 us; speedup vs baseline: 3.9703x; 2.3038x over previous
//
#include <hip/hip_runtime.h>

// 1-NN via 3-term bf16-split MFMA + provably-safe exact rescore.
// argmin_j ||x_i - y_j||^2 == argmin_j (0.5||y_j||^2 - x_i.y_j).
// Pass A (MFMA): d~ = h_j - (xhi.yhi + xhi.ylo + xlo.yhi), per-(q,slice) top-2 min.
// Pass B: candidates = {j : d~ <= min_q + EPS}; 1 candidate -> done; else exact
// fp32 rescore (serial or slice-rescan worklist) with (dist,idx)-lex atomicMin.
// EPS=0.0625 is >=30x the deterministic bf16-split error bound (~2e-3).

#define NQ 8192
#define NM 32768
#define ND 128
#define BT 256
#define NSLICE 8
#define SLICE (NM / NSLICE)   // 4096
#define QB 32                 // queries per block (pass A)
#define JCH 64                // j rows per LDS chunk
#define NCH (SLICE / JCH)     // 64
#define EPS 0.0625f
#define WLCAP 16384

using bf16x8 = __attribute__((ext_vector_type(8))) short;
using f32x4  = __attribute__((ext_vector_type(4))) float;

__device__ __forceinline__ unsigned short bf16r(float f) {
  unsigned u = __float_as_uint(f);
  u += 0x7FFFu + ((u >> 16) & 1u);
  return (unsigned short)(u >> 16);
}
__device__ __forceinline__ float bf2f(unsigned short h) {
  return __uint_as_float(((unsigned)h) << 16);
}
__device__ __forceinline__ unsigned long long packsd(float s, int j) {
  unsigned u = __float_as_uint(s);
  u ^= (u & 0x80000000u) ? 0xFFFFFFFFu : 0x80000000u;  // monotone float->uint
  return (((unsigned long long)u) << 32) | (unsigned)j;
}
__device__ __forceinline__ void gload_lds16(const void* g, void* l) {
  __builtin_amdgcn_global_load_lds(
      (const __attribute__((address_space(1))) void*)g,
      (__attribute__((address_space(3))) void*)l, 16, 0, 0);
}

// ---- split y -> chunk-XOR-swizzled bf16 hi/lo arrays; also zero worklist cnt ----
__global__ void splity_kernel(const float* __restrict__ y,
                              unsigned short* __restrict__ yh,
                              unsigned short* __restrict__ yl,
                              int* __restrict__ cnt) {
  if (blockIdx.x == 0 && threadIdx.x == 0) *cnt = 0;
  const int j = blockIdx.x * 2 + (threadIdx.x >> 7);
  const int c = threadIdx.x & 127;
  const float f = y[(size_t)j * ND + c];
  const unsigned short hb = bf16r(f);
  const unsigned short lb = bf16r(f - bf2f(hb));
  // 16B chunk (c>>3) stored at position (c>>3)^(j&7): bank swizzle baked in global
  const int off = ((((c >> 3) ^ (j & 7)) << 3) | (c & 7));
  yh[(size_t)j * ND + off] = hb;
  yl[(size_t)j * ND + off] = lb;
}

// ---- h[j] = 0.5*||y_j||^2 exact fp32 (k-ascending chain) ----
__global__ void hrow_kernel(const float* __restrict__ y, float* __restrict__ h) {
  const int j = blockIdx.x * blockDim.x + threadIdx.x;
  if (j >= NM) return;
  const float4* __restrict__ yp = (const float4*)(y + (size_t)j * ND);
  float s = 0.f;
#pragma unroll
  for (int u = 0; u < ND / 4; ++u) {
    const float4 v = yp[u];
    s = fmaf(v.x, v.x, s); s = fmaf(v.y, v.y, s);
    s = fmaf(v.z, v.z, s); s = fmaf(v.w, v.w, s);
  }
  h[j] = 0.5f * s;
}

// ---- pass A: MFMA approx distances, per-(q,slice) top-2 ----
__global__ __launch_bounds__(BT) void nnA_mfma(
    const float* __restrict__ x, const unsigned short* __restrict__ yh,
    const unsigned short* __restrict__ yl, const float* __restrict__ h,
    float* __restrict__ pv1, int* __restrict__ pi1, float* __restrict__ pv2) {
  __shared__ unsigned short ylds[2][JCH * ND];  // [hi/lo][64 rows x 256B], swizzled rows
  __shared__ float rv1[4][QB], rv2[4][QB];
  __shared__ int ri1[4][QB];
  const int t = threadIdx.x, lane = t & 63, w = t >> 6;
  const int l15 = lane & 15, lg = lane >> 4;
  const int slice = blockIdx.x & (NSLICE - 1);
  const int q0 = (blockIdx.x >> 3) * QB;

  // x fragments (hi/lo) built on the fly; A-frag: row=l15 (query), k=lg*8+i
  bf16x8 xh[2][4], xl[2][4];
#pragma unroll
  for (int qt = 0; qt < 2; ++qt)
#pragma unroll
    for (int ks = 0; ks < 4; ++ks) {
      const float* xp = x + (size_t)(q0 + qt * 16 + l15) * ND + ks * 32 + lg * 8;
      const float4 f0 = *(const float4*)xp;
      const float4 f1 = *(const float4*)(xp + 4);
      const float ff[8] = {f0.x, f0.y, f0.z, f0.w, f1.x, f1.y, f1.z, f1.w};
      bf16x8 vh, vl;
#pragma unroll
      for (int i = 0; i < 8; ++i) {
        const unsigned short hb = bf16r(ff[i]);
        vh[i] = (short)hb;
        vl[i] = (short)bf16r(ff[i] - bf2f(hb));
      }
      xh[qt][ks] = vh; xl[qt][ks] = vl;
    }

  float v1[8], v2[8]; int ix[8];
#pragma unroll
  for (int p = 0; p < 8; ++p) { v1[p] = 3.4e38f; v2[p] = 3.4e38f; ix[p] = 0; }

  const int r = w * 16 + l15;  // this lane's y-row within chunk (B-frag col = l15)
  const int rx = r & 7;

#pragma unroll 1
  for (int ch = 0; ch < NCH; ++ch) {
    const int jb = slice * SLICE + ch * JCH;
    const size_t gbase = (size_t)jb * ND;
#pragma unroll
    for (int s2 = 0; s2 < 4; ++s2) {
      const int o = s2 * 2048 + w * 512 + lane * 8;  // elems; wave-linear 16B/lane
      gload_lds16(yh + gbase + o, &ylds[0][s2 * 2048 + w * 512]);
      gload_lds16(yl + gbase + o, &ylds[1][s2 * 2048 + w * 512]);
    }
    __syncthreads();  // drains vmcnt -> LDS writes complete
    f32x4 a0 = {0.f, 0.f, 0.f, 0.f}, a1 = {0.f, 0.f, 0.f, 0.f};
#pragma unroll
    for (int ks = 0; ks < 4; ++ks) {
      const int bo = r * 256 + ((((ks << 2) | lg) ^ rx) << 4);  // XOR-unswizzle
      const bf16x8 byh = *(const bf16x8*)((const char*)&ylds[0][0] + bo);
      const bf16x8 byl = *(const bf16x8*)((const char*)&ylds[1][0] + bo);
      a0 = __builtin_amdgcn_mfma_f32_16x16x32_bf16(xh[0][ks], byh, a0, 0, 0, 0);
      a0 = __builtin_amdgcn_mfma_f32_16x16x32_bf16(xh[0][ks], byl, a0, 0, 0, 0);
      a0 = __builtin_amdgcn_mfma_f32_16x16x32_bf16(xl[0][ks], byh, a0, 0, 0, 0);
      a1 = __builtin_amdgcn_mfma_f32_16x16x32_bf16(xh[1][ks], byh, a1, 0, 0, 0);
      a1 = __builtin_amdgcn_mfma_f32_16x16x32_bf16(xh[1][ks], byl, a1, 0, 0, 0);
      a1 = __builtin_amdgcn_mfma_f32_16x16x32_bf16(xl[1][ks], byh, a1, 0, 0, 0);
    }
    const int jj = jb + r;
    const float hv = h[jj];
#pragma unroll
    for (int p = 0; p < 8; ++p) {
      const float s = hv - ((p < 4) ? a0[p] : a1[p - 4]);
      if (s < v1[p]) { v2[p] = v1[p]; v1[p] = s; ix[p] = jj; }
      else if (s < v2[p]) v2[p] = s;
    }
    __syncthreads();  // protect LDS before next stage
  }

  // reduce across the 16 lanes sharing each query (lanes [16g,16g+15], j=l15)
#pragma unroll
  for (int p = 0; p < 8; ++p) {
    float m1 = v1[p], m2 = v2[p]; int i1 = ix[p];
    for (int off = 1; off < 16; off <<= 1) {
      const float o1 = __shfl_xor(m1, off);
      const float o2 = __shfl_xor(m2, off);
      const int oi = __shfl_xor(i1, off);
      const float n2 = fminf(fmaxf(m1, o1), fminf(m2, o2));
      if (o1 < m1 || (o1 == m1 && oi < i1)) { m1 = o1; i1 = oi; }
      m2 = n2;
    }
    if (l15 == 0) {
      const int ql = (p >> 2) * 16 + lg * 4 + (p & 3);  // D-layout row
      rv1[w][ql] = m1; rv2[w][ql] = m2; ri1[w][ql] = i1;
    }
  }
  __syncthreads();
  if (t < QB) {
    float m1 = rv1[0][t], m2 = rv2[0][t]; int i1 = ri1[0][t];
#pragma unroll
    for (int w2 = 1; w2 < 4; ++w2) {
      const float o1 = rv1[w2][t], o2 = rv2[w2][t];
      const int oi = ri1[w2][t];
      const float n2 = fminf(fmaxf(m1, o1), fminf(m2, o2));
      if (o1 < m1 || (o1 == m1 && oi < i1)) { m1 = o1; i1 = oi; }
      m2 = n2;
    }
    pv1[(size_t)(q0 + t) * NSLICE + slice] = m1;
    pv2[(size_t)(q0 + t) * NSLICE + slice] = m2;
    pi1[(size_t)(q0 + t) * NSLICE + slice] = i1;
  }
}

// exact fp32 key; k-ascending chain (identical in B and C)
__device__ __forceinline__ unsigned long long exact_key(
    const float* __restrict__ x, const float* __restrict__ y,
    const float* __restrict__ h, int q, int j) {
  const float* xp = x + (size_t)q * ND;
  const float* yp = y + (size_t)j * ND;
  float dot = 0.f;
#pragma unroll
  for (int k = 0; k < ND; ++k) dot = fmaf(xp[k], yp[k], dot);
  return packsd(h[j] - dot, j);
}

// ---- pass B: candidate logic ----
__global__ void nnB_kernel(const float* __restrict__ x, const float* __restrict__ y,
                           const float* __restrict__ h, const float* __restrict__ lab,
                           const float* __restrict__ pv1, const int* __restrict__ pi1,
                           const float* __restrict__ pv2, float* __restrict__ out,
                           unsigned long long* __restrict__ packed,
                           int* __restrict__ mode, int* __restrict__ wl,
                           int* __restrict__ cnt) {
  const int q = blockIdx.x * blockDim.x + threadIdx.x;
  if (q >= NQ) return;
  float m = 3.4e38f;
  for (int s = 0; s < NSLICE; ++s) m = fminf(m, pv1[q * NSLICE + s]);
  const float thr = m + EPS;
  int singles[NSLICE], resc[NSLICE], ns = 0, nr = 0;
  for (int s = 0; s < NSLICE; ++s) {
    if (pv1[q * NSLICE + s] <= thr) {
      if (pv2[q * NSLICE + s] <= thr) resc[nr++] = s;
      else singles[ns++] = pi1[q * NSLICE + s];
    }
  }
  if (nr == 0) {
    if (ns == 1) { out[q] = lab[singles[0]]; mode[q] = 0; return; }
    unsigned long long b = ~0ull;
    for (int i = 0; i < ns; ++i) {
      const unsigned long long k = exact_key(x, y, h, q, singles[i]);
      b = k < b ? k : b;
    }
    out[q] = lab[(unsigned)(b & 0xFFFFFFFFull)];
    mode[q] = 0; return;
  }
  const int base = atomicAdd(cnt, nr);
  // write whatever fits (never leave holes below WLCAP; extra scans are harmless)
  for (int i = 0; i < nr; ++i)
    if (base + i < WLCAP) wl[base + i] = (q << 3) | resc[i];
  unsigned long long b = ~0ull;
  for (int i = 0; i < ns; ++i) {
    const unsigned long long k = exact_key(x, y, h, q, singles[i]);
    b = k < b ? k : b;
  }
  if (base + nr <= WLCAP) {
    packed[q] = b; mode[q] = 1;  // pass C fills the rest
  } else {  // overflow (practically impossible): resolve fully serial
    for (int i = 0; i < nr; ++i) {
      const int j0 = resc[i] * SLICE;
      for (int j = j0; j < j0 + SLICE; ++j) {
        const unsigned long long k = exact_key(x, y, h, q, j);
        b = k < b ? k : b;
      }
    }
    out[q] = lab[(unsigned)(b & 0xFFFFFFFFull)]; mode[q] = 0;
  }
}

// ---- pass C: rescan worklist slices, exact fp32, atomicMin ----
__global__ __launch_bounds__(BT) void nnC_kernel(
    const float* __restrict__ x, const float* __restrict__ y,
    const float* __restrict__ h, const int* __restrict__ wl,
    const int* __restrict__ cnt, unsigned long long* __restrict__ packed) {
  __shared__ float xs[ND];
  __shared__ unsigned long long wb[4];
  int n = *cnt; if (n > WLCAP) n = WLCAP;
  const int t = threadIdx.x, lane = t & 63, w = t >> 6;
  for (int e = blockIdx.x; e < n; e += gridDim.x) {
    const int v = wl[e], q = v >> 3, sl = v & 7;
    __syncthreads();
    if (t < ND) xs[t] = x[(size_t)q * ND + t];
    __syncthreads();
    unsigned long long best = ~0ull;
    for (int i = 0; i < SLICE / BT; ++i) {
      const int j = sl * SLICE + i * BT + t;
      const float* yp = y + (size_t)j * ND;
      float dot = 0.f;
#pragma unroll
      for (int k = 0; k < ND; ++k) dot = fmaf(xs[k], yp[k], dot);
      const unsigned long long kk = packsd(h[j] - dot, j);
      if (kk < best) best = kk;
    }
    for (int off = 32; off; off >>= 1) {
      const unsigned long long o = __shfl_xor(best, off);
      if (o < best) best = o;
    }
    if (lane == 0) wb[w] = best;
    __syncthreads();
    if (t == 0) {
      unsigned long long b = wb[0];
      for (int w2 = 1; w2 < 4; ++w2) if (wb[w2] < b) b = wb[w2];
      atomicMin(packed + q, b);
    }
  }
}

// ---- pass D: finalize pending queries ----
__global__ void nnD_kernel(const unsigned long long* __restrict__ packed,
                           const int* __restrict__ mode,
                           const float* __restrict__ lab, float* __restrict__ out) {
  const int q = blockIdx.x * blockDim.x + threadIdx.x;
  if (q >= NQ) return;
  if (mode[q]) out[q] = lab[(unsigned)(packed[q] & 0xFFFFFFFFull)];
}

// ---- fallback (round-2 kernel, known-passing) ----
template <int USE_H>
__global__ __launch_bounds__(BT, 2) void nn_fallback(
    const float* __restrict__ x, const float* __restrict__ y,
    const float* __restrict__ lab, const float* __restrict__ h,
    float* __restrict__ out) {
  const int t = threadIdx.x;
  const int q0 = blockIdx.x * 16;
  float bv[16]; int bi[16];
#pragma unroll
  for (int q = 0; q < 16; ++q) { bv[q] = 3.4e38f; bi[q] = 0; }
  for (int it = 0; it < NM / 512; ++it) {
    const int j0 = it * 512 + t, j1 = j0 + 256;
    const float4* __restrict__ yp0 = (const float4*)(y + (size_t)j0 * ND);
    const float4* __restrict__ yp1 = (const float4*)(y + (size_t)j1 * ND);
    float acc0[16], acc1[16];
#pragma unroll
    for (int q = 0; q < 16; ++q) { acc0[q] = 0.f; acc1[q] = 0.f; }
    float y20 = 0.f, y21 = 0.f;
#pragma unroll 1
    for (int kc = 0; kc < 4; ++kc) {
      float4 a0[8], a1[8];
#pragma unroll
      for (int u = 0; u < 8; ++u) { a0[u] = yp0[kc * 8 + u]; a1[u] = yp1[kc * 8 + u]; }
      if (USE_H == 0) {
#pragma unroll
        for (int u = 0; u < 8; ++u) {
          y20 = fmaf(a0[u].x, a0[u].x, y20); y20 = fmaf(a0[u].y, a0[u].y, y20);
          y20 = fmaf(a0[u].z, a0[u].z, y20); y20 = fmaf(a0[u].w, a0[u].w, y20);
          y21 = fmaf(a1[u].x, a1[u].x, y21); y21 = fmaf(a1[u].y, a1[u].y, y21);
          y21 = fmaf(a1[u].z, a1[u].z, y21); y21 = fmaf(a1[u].w, a1[u].w, y21);
        }
      }
#pragma unroll
      for (int q = 0; q < 16; ++q) {
        const float* __restrict__ xq = x + (size_t)(q0 + q) * ND + kc * 32;
        float s0 = acc0[q], s1 = acc1[q];
#pragma unroll
        for (int u = 0; u < 8; ++u) {
          const float4 xv = *(const float4*)(xq + u * 4);
          s0 = fmaf(a0[u].x, xv.x, s0); s0 = fmaf(a0[u].y, xv.y, s0);
          s0 = fmaf(a0[u].z, xv.z, s0); s0 = fmaf(a0[u].w, xv.w, s0);
          s1 = fmaf(a1[u].x, xv.x, s1); s1 = fmaf(a1[u].y, xv.y, s1);
          s1 = fmaf(a1[u].z, xv.z, s1); s1 = fmaf(a1[u].w, xv.w, s1);
        }
        acc0[q] = s0; acc1[q] = s1;
      }
    }
    float h0, h1;
    if (USE_H) { h0 = h[j0]; h1 = h[j1]; }
    else { h0 = 0.5f * y20; h1 = 0.5f * y21; }
#pragma unroll
    for (int q = 0; q < 16; ++q) {
      const float s0 = h0 - acc0[q], s1 = h1 - acc1[q];
      if (s0 < bv[q]) { bv[q] = s0; bi[q] = j0; }
      if (s1 < bv[q]) { bv[q] = s1; bi[q] = j1; }
    }
  }
  __shared__ float rv[4][16];
  __shared__ int ri[4][16];
  const int lane = t & 63, w = t >> 6;
#pragma unroll
  for (int q = 0; q < 16; ++q) {
    float v = bv[q]; int ixq = bi[q];
    for (int off = 32; off; off >>= 1) {
      const float ov = __shfl_down(v, off);
      const int oi = __shfl_down(ixq, off);
      if (ov < v || (ov == v && oi < ixq)) { v = ov; ixq = oi; }
    }
    if (lane == 0) { rv[w][q] = v; ri[w][q] = ixq; }
  }
  __syncthreads();
  if (t < 16) {
    float v = rv[0][t]; int ixq = ri[0][t];
#pragma unroll
    for (int w2 = 1; w2 < 4; ++w2) {
      const float ov = rv[w2][t]; const int oi = ri[w2][t];
      if (ov < v || (ov == v && oi < ixq)) { v = ov; ixq = oi; }
    }
    out[q0 + t] = lab[ixq];
  }
}

extern "C" void kernel_launch(void* const* d_in, const int* in_sizes, int n_in,
                              void* d_out, int out_size, void* d_ws, size_t ws_size,
                              hipStream_t stream) {
  const float* x = (const float*)d_in[0];
  const float* y = (const float*)d_in[1];
  const float* lab = (const float*)d_in[2];
  float* out = (float*)d_out;

  const size_t o_yh = 0;
  const size_t o_yl = o_yh + (size_t)NM * ND * 2;   // 8 MB
  const size_t o_h  = o_yl + (size_t)NM * ND * 2;   // +8 MB
  const size_t o_p1 = o_h + (size_t)NM * 4;
  const size_t o_p2 = o_p1 + (size_t)NQ * NSLICE * 4;
  const size_t o_i1 = o_p2 + (size_t)NQ * NSLICE * 4;
  const size_t o_pk = o_i1 + (size_t)NQ * NSLICE * 4;
  const size_t o_wl = o_pk + (size_t)NQ * 8;
  const size_t o_md = o_wl + (size_t)WLCAP * 4;
  const size_t o_ct = o_md + (size_t)NQ * 4;
  const size_t need = o_ct + 16;

  if (ws_size >= need) {
    char* W = (char*)d_ws;
    unsigned short* yh = (unsigned short*)(W + o_yh);
    unsigned short* yl = (unsigned short*)(W + o_yl);
    float* h = (float*)(W + o_h);
    float* pv1 = (float*)(W + o_p1);
    float* pv2 = (float*)(W + o_p2);
    int* pi1 = (int*)(W + o_i1);
    unsigned long long* packed = (unsigned long long*)(W + o_pk);
    int* wl = (int*)(W + o_wl);
    int* mode = (int*)(W + o_md);
    int* cnt = (int*)(W + o_ct);
    splity_kernel<<<NM / 2, BT, 0, stream>>>(y, yh, yl, cnt);
    hrow_kernel<<<NM / BT, BT, 0, stream>>>(y, h);
    nnA_mfma<<<(NQ / QB) * NSLICE, BT, 0, stream>>>(x, yh, yl, h, pv1, pi1, pv2);
    nnB_kernel<<<NQ / BT, BT, 0, stream>>>(x, y, h, lab, pv1, pi1, pv2,
                                           out, packed, mode, wl, cnt);
    nnC_kernel<<<256, BT, 0, stream>>>(x, y, h, wl, cnt, packed);
    nnD_kernel<<<NQ / BT, BT, 0, stream>>>(packed, mode, lab, out);
  } else if (ws_size >= (size_t)NM * 4) {
    float* h = (float*)d_ws;
    hrow_kernel<<<NM / BT, BT, 0, stream>>>(y, h);
    nn_fallback<1><<<NQ / 16, BT, 0, stream>>>(x, y, lab, h, out);
  } else {
    nn_fallback<0><<<NQ / 16, BT, 0, stream>>>(x, y, lab, nullptr, out);
  }
}